// Round 1
// baseline (734.008 us; speedup 1.0000x reference)
//
#include <hip/hip_runtime.h>
#include <math.h>

#define NB      32768
#define NPMT    253
#define MAXIT   50
// step = 0.1 * 2^-k ; active while step >= 1e-4  <=>  k <= 9
#define KMAX_ACTIVE 9

__global__ __launch_bounds__(256) void walldist_kernel(
    const float* __restrict__ X,
    const float* __restrict__ pmt,
    const float* __restrict__ tpc_r_p,
    float2* __restrict__ out)
{
    __shared__ float2 tab[12];   // (cos(step_k), sin(step_k))
    const int t = threadIdx.x;
    if (t < 12) {
        float step = 0.1f * exp2f(-(float)t);
        float ss, cs;
        sincosf(step, &ss, &cs);
        tab[t] = make_float2(cs, ss);
    }
    __syncthreads();

    const int total = NB * NPMT;
    const int q = blockIdx.x * blockDim.x + t;
    if (q >= total) return;

    const int b = q / NPMT;          // compiler emits magic-mul
    const int p = q - b * NPMT;

    const float R  = tpc_r_p[0];
    const float ex = X[2 * b],   ey = X[2 * b + 1];
    const float px = pmt[2 * p], py = pmt[2 * p + 1];

    // theta0 = theta_event + 0.5 * wrap(theta_pmt - theta_event), as in ref
    const float the  = atan2f(ey, ex);
    const float thp  = atan2f(py, px);
    const float diff = thp - the;
    const float delta = atan2f(sinf(diff), cosf(diff));
    const float th0 = fmaf(0.5f, delta, the);
    float c, s;
    sincosf(th0, &s, &c);

    // d_event(c,s) = sqrt(R^2 + |e|^2 - 2R(ex*c + ey*s)) = sqrt(Ae - Bex*c - Bey*s)
    const float Ae  = fmaf(ex, ex, fmaf(ey, ey, R * R));
    const float Bex = 2.0f * R * ex, Bey = 2.0f * R * ey;
    const float Ap  = fmaf(px, px, fmaf(py, py, R * R));
    const float Bpx = 2.0f * R * px, Bpy = 2.0f * R * py;

    auto loss = [&](float cc, float sn) -> float {
        float ve = fmaf(-Bex, cc, Ae); ve = fmaf(-Bey, sn, ve);
        float vp = fmaf(-Bpx, cc, Ap); vp = fmaf(-Bpy, sn, vp);
        return sqrtf(fmaxf(ve, 0.0f)) + sqrtf(fmaxf(vp, 0.0f));
    };

    float l0 = loss(c, s);
    int   k  = 0;
    float cs = tab[0].x, ss = tab[0].y;

    for (int it = 0; it < MAXIT; ++it) {
        const bool act = (k <= KMAX_ACTIVE);
        if (!__any(act)) break;            // wave-uniform exit

        // rotate current point by +step and -step
        const float t1 = c * cs, t2 = s * ss, t3 = s * cs, t4 = c * ss;
        const float cp = t1 - t2, sp = t3 + t4;   // theta + step
        const float cm = t1 + t2, sm = t3 - t4;   // theta - step

        const float lp = loss(cp, sp);
        const float lm = loss(cm, sm);

        const bool bp = act && (lp < l0);                 // prefer +step (ref order)
        const bool bm = act && !bp && (lm < l0);
        const bool halve = act && !bp && !bm;

        c  = bp ? cp : (bm ? cm : c);
        s  = bp ? sp : (bm ? sm : s);
        l0 = bp ? lp : (bm ? lm : l0);

        if (halve) {
            ++k;
            const int ki = (k < 12) ? k : 11;
            const float2 tt = tab[ki];
            cs = tt.x; ss = tt.y;
        }
    }

    // is_center: |e| < 1e-8  ->  theta = theta_pmt
    if (fmaf(ex, ex, ey * ey) < 1e-16f) {
        const float rp = sqrtf(fmaf(px, px, py * py));
        c = px / rp; s = py / rp;
    }

    float ve = fmaf(-Bex, c, Ae); ve = fmaf(-Bey, s, ve);
    float vp = fmaf(-Bpx, c, Ap); vp = fmaf(-Bpy, s, vp);
    out[q] = make_float2(sqrtf(fmaxf(ve, 0.0f)), sqrtf(fmaxf(vp, 0.0f)));
}

extern "C" void kernel_launch(void* const* d_in, const int* in_sizes, int n_in,
                              void* d_out, int out_size, void* d_ws, size_t ws_size,
                              hipStream_t stream) {
    const float* X   = (const float*)d_in[0];
    const float* pmt = (const float*)d_in[1];
    const float* R   = (const float*)d_in[2];
    float2* out = (float2*)d_out;

    const int total  = NB * NPMT;                 // 8,290,304 pairs
    const int block  = 256;
    const int grid   = (total + block - 1) / block;
    walldist_kernel<<<grid, block, 0, stream>>>(X, pmt, R, out);
}

// Round 3
// 248.448 us; speedup vs baseline: 2.9544x; 2.9544x over previous
//
#include <hip/hip_runtime.h>
#include <math.h>

#define NB      32768
#define NPMT    253
#define MAXIT   50

// Reference-faithful greedy descent (per-lane compressed halving, R0 semantics)
// made branchless: no LDS table, no divergent halve branch, squared-loss compares.
__global__ __launch_bounds__(256) void walldist_kernel(
    const float* __restrict__ X,
    const float* __restrict__ pmt,
    const float* __restrict__ tpc_r_p,
    float2* __restrict__ out)
{
    const int total = NB * NPMT;
    const int q = blockIdx.x * blockDim.x + threadIdx.x;
    if (q >= total) return;

    const int b = q / NPMT;          // magic-mul
    const int p = q - b * NPMT;

    const float R  = tpc_r_p[0];
    const float ex = X[2 * b],   ey = X[2 * b + 1];
    const float px = pmt[2 * p], py = pmt[2 * p + 1];

    // theta0 exactly as the reference (and as R0, which passed):
    const float the   = atan2f(ey, ex);
    const float thp   = atan2f(py, px);
    const float diff  = thp - the;
    const float delta = atan2f(sinf(diff), cosf(diff));
    const float th0   = fmaf(0.5f, delta, the);
    float c, s;
    sincosf(th0, &s, &c);

    // d_event^2 = Ae - Bex*c - Bey*s ; d_pmt^2 = Ap - Bpx*c - Bpy*s
    const float Ae  = fmaf(ex, ex, fmaf(ey, ey, R * R));
    const float Bex = 2.0f * R * ex, Bey = 2.0f * R * ey;
    const float Ap  = fmaf(px, px, fmaf(py, py, R * R));
    const float Bpx = 2.0f * R * px, Bpy = 2.0f * R * py;

    // carried state: squared loss S0 = (sqrt(a)+sqrt(b))^2 = a + b + 2*sqrt(a*b)
    float a0 = fmaf(-Bex, c, Ae); a0 = fmaf(-Bey, s, a0); a0 = fmaxf(a0, 0.0f);
    float b0 = fmaf(-Bpx, c, Ap); b0 = fmaf(-Bpy, s, b0); b0 = fmaxf(b0, 0.0f);
    float S0 = a0 + b0 + 2.0f * __builtin_amdgcn_sqrtf(a0 * b0);

    // (cs, ss) = (cos(step), sin(step)), step = 0.1 * 2^-k
    float cs = 0.995004165278025766f;   // cos(0.1)
    float ss = 0.099833416646828152f;   // sin(0.1)

    #pragma unroll 1
    for (int it = 0; it < MAXIT; ++it) {
        // active while step >= TOL=1e-4: sin(1.953e-4) vs sin(9.77e-5)
        const bool act = (ss > 1.5e-4f);
        if (!__any(act)) break;

        // rotate current point by +step / -step
        const float t1 = c * cs, t2 = s * ss, t3 = s * cs, t4 = c * ss;
        const float cp = t1 - t2, sp = t3 + t4;
        const float cm = t1 + t2, sm = t3 - t4;

        float ap = fmaf(-Bex, cp, Ae); ap = fmaf(-Bey, sp, ap);
        float bp = fmaf(-Bpx, cp, Ap); bp = fmaf(-Bpy, sp, bp);
        float am = fmaf(-Bex, cm, Ae); am = fmaf(-Bey, sm, am);
        float bq = fmaf(-Bpx, cm, Ap); bq = fmaf(-Bpy, sm, bq);

        const float Sp = ap + bp + 2.0f * __builtin_amdgcn_sqrtf(fmaxf(ap * bp, 0.0f));
        const float Sm = am + bq + 2.0f * __builtin_amdgcn_sqrtf(fmaxf(am * bq, 0.0f));

        const bool mvp = act && (Sp < S0);                 // ref tests +step first
        const bool mvm = act && !mvp && (Sm < S0);
        const bool hlv = act && !mvp && !mvm;

        c  = mvp ? cp : (mvm ? cm : c);
        s  = mvp ? sp : (mvm ? sm : s);
        S0 = mvp ? Sp : (mvm ? Sm : S0);

        // branchless half-angle: (cos h, sin h) -> (cos h/2, sin h/2)
        const float n2  = fmaf(2.0f, cs, 2.0f);            // 2 + 2*cs
        const float inv = __builtin_amdgcn_rsqf(n2);       // 1/sqrt(2+2cs)
        const float csh = 0.5f * n2 * inv;                 // sqrt((1+cs)/2)
        const float ssh = ss * inv;                        // ss / sqrt(2+2cs)
        cs = hlv ? csh : cs;
        ss = hlv ? ssh : ss;
    }

    // is_center: |e| < 1e-8  ->  theta = theta_pmt
    if (fmaf(ex, ex, ey * ey) < 1e-16f) {
        const float rp = sqrtf(fmaf(px, px, py * py));
        c = px / rp; s = py / rp;
    }

    float ve = fmaf(-Bex, c, Ae); ve = fmaf(-Bey, s, ve);
    float vp = fmaf(-Bpx, c, Ap); vp = fmaf(-Bpy, s, vp);
    out[q] = make_float2(sqrtf(fmaxf(ve, 0.0f)), sqrtf(fmaxf(vp, 0.0f)));
}

extern "C" void kernel_launch(void* const* d_in, const int* in_sizes, int n_in,
                              void* d_out, int out_size, void* d_ws, size_t ws_size,
                              hipStream_t stream) {
    const float* X   = (const float*)d_in[0];
    const float* pmt = (const float*)d_in[1];
    const float* R   = (const float*)d_in[2];
    float2* out = (float2*)d_out;

    const int total = NB * NPMT;                  // 8,290,304 pairs
    const int block = 256;
    const int grid  = (total + block - 1) / block;
    walldist_kernel<<<grid, block, 0, stream>>>(X, pmt, R, out);
}